// Round 1
// baseline (1516.181 us; speedup 1.0000x reference)
//
#include <hip/hip_runtime.h>
#include <cstdint>

typedef _Float16 f16;
typedef __attribute__((ext_vector_type(8))) _Float16 half8;
typedef __attribute__((ext_vector_type(4))) _Float16 half4;
typedef __attribute__((ext_vector_type(4))) float f32x4;

#define NB    8
#define SEQ   2048
#define MODELD 2048
#define ACT_ELEMS (16384L * 2048L)
#define W_ELEMS   (2048L * 2048L)

__device__ __forceinline__ void gld_lds16(const void* g, void* l) {
  __builtin_amdgcn_global_load_lds(
      (const __attribute__((address_space(1))) unsigned int*)(uintptr_t)g,
      (__attribute__((address_space(3))) unsigned int*)(uintptr_t)l,
      16, 0, 0);
}

// C = alpha * A * B^T.  A: M x K row-major, B: N x K row-major, K contiguous.
// 1D grid; work decoded so XCD (blockIdx%8) owns a contiguous work range,
// traversed in 4x4 block supertiles (L2 locality). Tile 128x128, BK=64,
// 4 waves x (4x4 mfma_f32_16x16x32_f16), global_load_lds width-16 staging.
template <typename OutT, bool TRANS_OUT>
__global__ __launch_bounds__(256) void gemm_bt(
    const f16* __restrict__ A, long lda, long sA,
    const f16* __restrict__ Bm, long ldb, long sB,
    OutT* __restrict__ C, long ldc, long sC,
    int K, float alpha, int tilesX, int tilesY)
{
  const int tid  = threadIdx.x;
  const int lane = tid & 63;
  const int wave = tid >> 6;

  // ---- XCD-contiguous supertile decode ----
  const unsigned total = gridDim.x;
  const unsigned per   = total >> 3;                      // work items per XCD
  const unsigned wid   = (blockIdx.x & 7) * per + (blockIdx.x >> 3);
  const unsigned perB  = (unsigned)(tilesX * tilesY);
  const unsigned bz    = wid / perB;
  unsigned t           = wid - bz * perB;
  const unsigned sx    = (unsigned)tilesX >> 2;           // supertile columns
  const unsigned st    = t >> 4;                          // 16 blocks / supertile
  const unsigned w     = t & 15;
  const unsigned sr    = st / sx;
  const unsigned sc    = st - sr * sx;
  const int by = (int)(sr * 4 + (w >> 2));
  const int bx = (int)(sc * 4 + (w & 3));

  const f16* Ab = A + (long)bz * sA;
  const f16* Bb = Bm + (long)bz * sB;
  OutT*      Cb = C + (long)bz * sC;

  const int row0 = by * 128;
  const int col0 = bx * 128;

  __shared__ f16 lds[2 * 8192];   // A tile 16KB | B tile 16KB
  f16* ldsA = lds;
  f16* ldsB = lds + 8192;

  const int srow   = lane & 7;
  const int schunk = lane >> 3;

  f32x4 acc[4][4];
#pragma unroll
  for (int i = 0; i < 4; i++)
#pragma unroll
    for (int j = 0; j < 4; j++) {
      f32x4 z = {0.f, 0.f, 0.f, 0.f};
      acc[i][j] = z;
    }

  const int wm = wave >> 1;
  const int wn = wave & 1;

  const int fr_sub   = (lane & 7) * 8;
  const int fr_gadd  = ((lane & 15) >> 3) * 512;
  const int fr_chunk = (lane >> 4) * 64;

  for (int k0 = 0; k0 < K; k0 += 64) {
#pragma unroll
    for (int i = 0; i < 4; i++) {
      const int g = wave * 4 + i;
      gld_lds16(Ab + (long)(row0 + g * 8 + srow) * lda + k0 + schunk * 8,
                ldsA + g * 512);
      gld_lds16(Bb + (long)(col0 + g * 8 + srow) * ldb + k0 + schunk * 8,
                ldsB + g * 512);
    }
    __syncthreads();

#pragma unroll
    for (int ks = 0; ks < 2; ks++) {
      half8 af[4], bf[4];
#pragma unroll
      for (int t2 = 0; t2 < 4; t2++) {
        const int offA = (wm * 8 + t2 * 2) * 512 + fr_gadd + ks * 256 + fr_chunk + fr_sub;
        af[t2] = *(const half8*)(ldsA + offA);
        const int offB = (wn * 8 + t2 * 2) * 512 + fr_gadd + ks * 256 + fr_chunk + fr_sub;
        bf[t2] = *(const half8*)(ldsB + offB);
      }
#pragma unroll
      for (int i = 0; i < 4; i++)
#pragma unroll
        for (int j = 0; j < 4; j++)
          acc[i][j] = __builtin_amdgcn_mfma_f32_16x16x32_f16(af[i], bf[j], acc[i][j], 0, 0, 0);
    }
    __syncthreads();
  }

  const int lrow = (lane >> 4) * 4;
  const int lcol = lane & 15;
#pragma unroll
  for (int tm = 0; tm < 4; tm++) {
#pragma unroll
    for (int tn = 0; tn < 4; tn++) {
      const int r0 = row0 + wm * 64 + tm * 16 + lrow;
      const int c  = col0 + wn * 64 + tn * 16 + lcol;
      if constexpr (!TRANS_OUT) {
#pragma unroll
        for (int j = 0; j < 4; j++)
          Cb[(long)(r0 + j) * ldc + c] = (OutT)(acc[tm][tn][j] * alpha);
      } else {
        half4 h;
#pragma unroll
        for (int j = 0; j < 4; j++) h[j] = (f16)(acc[tm][tn][j] * alpha);
        *(half4*)(&Cb[(long)c * ldc + r0]) = h;
      }
    }
  }
}

__global__ __launch_bounds__(256) void f32_to_f16_k(const float* __restrict__ in,
                                                    f16* __restrict__ out, int n4) {
  const int i = blockIdx.x * 256 + threadIdx.x;
  if (i < n4) {
    const float4 x = ((const float4*)in)[i];
    half4 h;
    h[0] = (f16)x.x; h[1] = (f16)x.y; h[2] = (f16)x.z; h[3] = (f16)x.w;
    ((half4*)out)[i] = h;
  }
}

// out[j][i] = (f16)in[i][j], n x n (n multiple of 64)
__global__ __launch_bounds__(256) void transpose_f32_f16_k(const float* __restrict__ in,
                                                           f16* __restrict__ out, int n) {
  __shared__ float tile[64][65];
  const int bx = blockIdx.x, by = blockIdx.y;
  const int tr = threadIdx.x >> 4;
  const int tc = (threadIdx.x & 15) * 4;
  const int r0 = by * 64, c0 = bx * 64;
#pragma unroll
  for (int i = 0; i < 4; i++) {
    const float4 v = *(const float4*)&in[(long)(r0 + tr + i * 16) * n + c0 + tc];
    tile[tr + i * 16][tc + 0] = v.x;
    tile[tr + i * 16][tc + 1] = v.y;
    tile[tr + i * 16][tc + 2] = v.z;
    tile[tr + i * 16][tc + 3] = v.w;
  }
  __syncthreads();
#pragma unroll
  for (int i = 0; i < 4; i++) {
    const int orow = tr + i * 16;
    half4 h;
#pragma unroll
    for (int j = 0; j < 4; j++) h[j] = (f16)tile[tc + j][orow];
    *(half4*)&out[(long)(c0 + orow) * n + r0 + tc] = h;
  }
}

// one block per row: masked softmax over 2048 f16 scores -> f16 probs
__global__ __launch_bounds__(256) void softmax_mask_k(const f16* __restrict__ S,
                                                      f16* __restrict__ P,
                                                      const int* __restrict__ kmask,
                                                      const int* __restrict__ is_causal_p) {
  const int row = blockIdx.x;
  const int b   = row >> 11;
  const int qi  = row & 2047;
  const int tid = threadIdx.x;
  const int causal = *is_causal_p;

  const f16* srow = S + (long)row * 2048;
  const int* mrow = kmask + (long)b * 2048;

  const half8 x  = ((const half8*)srow)[tid];
  const int4  m0 = ((const int4*)mrow)[tid * 2];
  const int4  m1 = ((const int4*)mrow)[tid * 2 + 1];
  const int   mk[8] = {m0.x, m0.y, m0.z, m0.w, m1.x, m1.y, m1.z, m1.w};
  const int   kb = tid * 8;

  float v[8];
  float vmax = -INFINITY;
#pragma unroll
  for (int e = 0; e < 8; e++) {
    const bool keep = (mk[e] != 0) || (causal && (kb + e > qi));
    v[e] = keep ? (float)x[e] : -INFINITY;
    vmax = fmaxf(vmax, v[e]);
  }
#pragma unroll
  for (int o = 32; o > 0; o >>= 1) vmax = fmaxf(vmax, __shfl_xor(vmax, o, 64));

  __shared__ float red[8];
  if ((tid & 63) == 0) red[tid >> 6] = vmax;
  __syncthreads();
  vmax = fmaxf(fmaxf(red[0], red[1]), fmaxf(red[2], red[3]));

  float p[8];
  float s = 0.f;
#pragma unroll
  for (int e = 0; e < 8; e++) { p[e] = __expf(v[e] - vmax); s += p[e]; }
#pragma unroll
  for (int o = 32; o > 0; o >>= 1) s += __shfl_xor(s, o, 64);
  if ((tid & 63) == 0) red[4 + (tid >> 6)] = s;
  __syncthreads();
  s = red[4] + red[5] + red[6] + red[7];
  const float inv = 1.0f / s;

  half8 h;
#pragma unroll
  for (int e = 0; e < 8; e++) h[e] = (f16)(p[e] * inv);
  ((half8*)(P + (long)row * 2048))[tid] = h;
}

extern "C" void kernel_launch(void* const* d_in, const int* in_sizes, int n_in,
                              void* d_out, int out_size, void* d_ws, size_t ws_size,
                              hipStream_t stream) {
  const float* query = (const float*)d_in[0];
  const float* key   = (const float*)d_in[1];
  const float* value = (const float*)d_in[2];
  const float* Wq    = (const float*)d_in[3];
  const float* Wk    = (const float*)d_in[4];
  const float* Wv    = (const float*)d_in[5];
  const int*   kmask = (const int*)d_in[6];
  const int*   iscau = (const int*)d_in[7];

  char* ws = (char*)d_ws;
  f16* buf1 = (f16*)ws;                          // qf -> vf
  f16* buf2 = (f16*)(ws + ACT_ELEMS * 2);        // WqT|WkT -> q' -> P
  f16* buf3 = (f16*)(ws + 2 * ACT_ELEMS * 2);    // X -> kf -> vT
  f16* w2   = (f16*)(ws + 3 * ACT_ELEMS * 2);    // Wv f16 (persists)
  f16* WqT  = buf2;
  f16* WkT  = buf2 + W_ELEMS;
  f16* Xm   = buf3;                              // X = scale * Wk^T * Wq  (= M^T)

  const dim3 blk(256);
  const int cw = (int)(W_ELEMS / 4 + 255) / 256;
  const int ca = (int)(ACT_ELEMS / 4 + 255) / 256;
  const float scale = 0.022097086912079608f;     // 1/sqrt(2048)
  const long SB = (long)SEQ * SEQ;

  // ---- weight preprocessing ----
  transpose_f32_f16_k<<<dim3(32, 32), blk, 0, stream>>>(Wq, WqT, MODELD);
  transpose_f32_f16_k<<<dim3(32, 32), blk, 0, stream>>>(Wk, WkT, MODELD);
  f32_to_f16_k<<<cw, blk, 0, stream>>>(Wv, w2, (int)(W_ELEMS / 4));

  // X = scale * Wk^T * Wq   (2048^3, writes buf3)
  gemm_bt<f16, false><<<256, blk, 0, stream>>>(
      WkT, MODELD, 0, WqT, MODELD, 0, Xm, MODELD, 0, MODELD, scale, 16, 16);

  // q' = query * X^T = scale * query * Wq^T * Wk   (reads buf1,buf3; writes buf2)
  f32_to_f16_k<<<ca, blk, 0, stream>>>(query, buf1, (int)(ACT_ELEMS / 4));
  gemm_bt<f16, false><<<2048, blk, 0, stream>>>(
      buf1, MODELD, 0, Xm, MODELD, 0, buf2, MODELD, 0, MODELD, 1.0f, 16, 128);

  // scores(f16, in d_out) = q' * key^T   (batched; X dead -> kf in buf3)
  f32_to_f16_k<<<ca, blk, 0, stream>>>(key, buf3, (int)(ACT_ELEMS / 4));
  gemm_bt<f16, false><<<2048, blk, 0, stream>>>(
      buf2, MODELD, SB, buf3, MODELD, SB, (f16*)d_out, SEQ, SB, MODELD, 1.0f, 16, 16);

  // softmax: d_out(f16) -> P in buf2 (q' dead)
  softmax_mask_k<<<NB * SEQ, blk, 0, stream>>>((const f16*)d_out, buf2, kmask, iscau);

  // v^T = (value * Wv^T)^T, transposed epilogue (vf in buf1, vT in buf3)
  f32_to_f16_k<<<ca, blk, 0, stream>>>(value, buf1, (int)(ACT_ELEMS / 4));
  gemm_bt<f16, true><<<2048, blk, 0, stream>>>(
      buf1, MODELD, SB, w2, MODELD, 0, buf3, SEQ, SB, MODELD, 1.0f, 16, 16);

  // out(f32) = P * v = P * (v^T)^T
  gemm_bt<float, false><<<2048, blk, 0, stream>>>(
      buf2, SEQ, SB, buf3, SEQ, SB, (float*)d_out, SEQ, SB, SEQ, 1.0f, 16, 16);

  (void)in_sizes; (void)n_in; (void)out_size; (void)ws_size;
}

// Round 2
// 1132.847 us; speedup vs baseline: 1.3384x; 1.3384x over previous
//
#include <hip/hip_runtime.h>
#include <cstdint>

typedef _Float16 f16;
typedef __attribute__((ext_vector_type(8))) _Float16 half8;
typedef __attribute__((ext_vector_type(4))) _Float16 half4;
typedef __attribute__((ext_vector_type(4))) float f32x4;

#define NB    8
#define SEQ   2048
#define MODELD 2048
#define ACT_ELEMS (16384L * 2048L)
#define W_ELEMS   (2048L * 2048L)

__device__ __forceinline__ void gld_lds16(const void* g, void* l) {
  __builtin_amdgcn_global_load_lds(
      (const __attribute__((address_space(1))) unsigned int*)(uintptr_t)g,
      (__attribute__((address_space(3))) unsigned int*)(uintptr_t)l,
      16, 0, 0);
}

// C = alpha * A * B^T.  A: M x K row-major, B: N x K row-major (K contiguous).
// 256x256 tile, BK=32, 8 waves (2Mx4N), per-wave 128x64 output.
// LDS: 4-slot ring (A 4x16KB | B 4x16KB = 128KB dynamic). While computing
// K-tile t (slot t&3), tile t+3 is staged into slot (t+3)&3 == (t-1)&3 (free
// since tile t-1's final barrier). Counted s_waitcnt vmcnt(8) once per K-tile
// guarantees tile t+1 landed while t+2/t+3 stay in flight (never drains to 0).
// LDS layout per slot: 16 groups of (16 rows x 32 k), element (g, lane) at
// g*512 + lane*8 f16 — matches global_load_lds's base+lane*16B linear write
// (src lane: row=lane&15, kchunk=lane>>4) AND the mfma_16x16x32 frag read
// (lane-linear 16B => zero bank conflicts, measured 0 on the 128^2 ancestor).
template <typename OutT, bool TRANS_OUT>
__global__ __launch_bounds__(512, 2) void gemm256_bt(
    const f16* __restrict__ A, long lda, long sA,
    const f16* __restrict__ Bm, long ldb, long sB,
    OutT* __restrict__ C, long ldc, long sC,
    int K, float alpha, int tilesX, int tilesY)
{
  extern __shared__ f16 smem[];
  const int tid  = threadIdx.x;
  const int lane = tid & 63;
  const int wave = tid >> 6;

  // ---- XCD-contiguous supertile decode (total % 8 == 0 by construction) ----
  const unsigned total = gridDim.x;
  const unsigned per   = total >> 3;
  const unsigned wid   = (blockIdx.x & 7) * per + (blockIdx.x >> 3);
  const unsigned perB  = (unsigned)(tilesX * tilesY);
  const unsigned bz    = wid / perB;
  unsigned t0          = wid - bz * perB;
  const unsigned sx    = (unsigned)tilesX >> 2;      // supertile columns
  const unsigned st    = t0 >> 4;                    // 16 blocks / supertile
  const unsigned w     = t0 & 15;
  const unsigned sr    = st / sx;
  const unsigned sc    = st - sr * sx;
  const int by = (int)(sr * 4 + (w >> 2));
  const int bx = (int)(sc * 4 + (w & 3));

  const f16* Ab = A + (long)bz * sA;
  const f16* Bb = Bm + (long)bz * sB;
  OutT*      Cb = C + (long)bz * sC;

  const int row0 = by * 256;
  const int col0 = bx * 256;

  const int r16 = lane & 15;     // staged row within 16-row group
  const int kc  = lane >> 4;     // staged k-chunk (8 f16)
  const int wm  = wave >> 2;     // 0..1  (row half)
  const int wn  = wave & 3;      // 0..3  (col quarter)

  f16* ldsA = smem;              // 4 slots x 8192 f16
  f16* ldsB = smem + 32768;      // 4 slots x 8192 f16

  const int T = K >> 5;          // K-tiles of 32

  f32x4 acc[8][4];
#pragma unroll
  for (int m = 0; m < 8; m++)
#pragma unroll
    for (int n = 0; n < 4; n++) {
      f32x4 z = {0.f, 0.f, 0.f, 0.f};
      acc[m][n] = z;
    }

  // stage: piece p stages group g = p*8+wave (16 rows x 32 k = 1KB per wave)
#define STAGE_A(u_, sw_)                                                   \
  do {                                                                     \
    const long ku_ = (long)(u_) * 32;                                      \
    _Pragma("unroll")                                                      \
    for (int p_ = 0; p_ < 2; ++p_) {                                       \
      const int g_ = p_ * 8 + wave;                                        \
      gld_lds16(Ab + (long)(row0 + g_ * 16 + r16) * lda + ku_ + kc * 8,    \
                ldsA + (sw_) * 8192 + g_ * 512);                           \
    }                                                                      \
  } while (0)
#define STAGE_B(u_, sw_)                                                   \
  do {                                                                     \
    const long ku_ = (long)(u_) * 32;                                      \
    _Pragma("unroll")                                                      \
    for (int p_ = 0; p_ < 2; ++p_) {                                       \
      const int g_ = p_ * 8 + wave;                                        \
      gld_lds16(Bb + (long)(col0 + g_ * 16 + r16) * ldb + ku_ + kc * 8,    \
                ldsB + (sw_) * 8192 + g_ * 512);                           \
    }                                                                      \
  } while (0)

  // ---- prologue: stage tiles 0,1,2 (12 loads/thread) ----
  const int u1 = (T > 1) ? 1 : 0;
  const int u2 = (T > 2) ? 2 : T - 1;
  STAGE_A(0, 0);  STAGE_B(0, 0);
  STAGE_A(u1, 1); STAGE_B(u1, 1);
  STAGE_A(u2, 2); STAGE_B(u2, 2);
  asm volatile("s_waitcnt vmcnt(8)" ::: "memory");   // tile 0 landed
  __builtin_amdgcn_s_barrier();

  for (int t = 0; t < T; ++t) {
    const int s  = t & 3;
    const int sw = (t + 3) & 3;                       // == (t-1)&3: free slot
    const int u  = (t + 3 < T) ? t + 3 : T - 1;       // clamp: uniform counts
    const f16* As = ldsA + s * 8192;
    const f16* Bs = ldsB + s * 8192;

    half8 af[4], bf[4];

    // ---------- phase 0: m-frags 0..3 ----------
#pragma unroll
    for (int m = 0; m < 4; m++)
      af[m] = *(const half8*)(As + (wm * 8 + m) * 512 + lane * 8);
#pragma unroll
    for (int n = 0; n < 4; n++)
      bf[n] = *(const half8*)(Bs + (wn * 4 + n) * 512 + lane * 8);
    STAGE_A(u, sw);
    __builtin_amdgcn_s_barrier();
    __builtin_amdgcn_s_setprio(1);
#pragma unroll
    for (int m = 0; m < 4; m++)
#pragma unroll
      for (int n = 0; n < 4; n++)
        acc[m][n] = __builtin_amdgcn_mfma_f32_16x16x32_f16(af[m], bf[n], acc[m][n], 0, 0, 0);
    __builtin_amdgcn_s_setprio(0);
    __builtin_amdgcn_s_barrier();

    // ---------- phase 1: m-frags 4..7 (reuse bf) ----------
#pragma unroll
    for (int m = 0; m < 4; m++)
      af[m] = *(const half8*)(As + (wm * 8 + 4 + m) * 512 + lane * 8);
    STAGE_B(u, sw);
    // counted wait: outstanding = {t+2: 4, t+3: 4}; guarantees t+1 landed.
    asm volatile("s_waitcnt vmcnt(8)" ::: "memory");
    __builtin_amdgcn_s_barrier();
    __builtin_amdgcn_s_setprio(1);
#pragma unroll
    for (int m = 0; m < 4; m++)
#pragma unroll
      for (int n = 0; n < 4; n++)
        acc[4 + m][n] = __builtin_amdgcn_mfma_f32_16x16x32_f16(af[m], bf[n], acc[4 + m][n], 0, 0, 0);
    __builtin_amdgcn_s_setprio(0);
    __builtin_amdgcn_s_barrier();
  }
#undef STAGE_A
#undef STAGE_B

  // drain staging before the block can retire (LDS may be reallocated)
  asm volatile("s_waitcnt vmcnt(0)" ::: "memory");

  // ---- epilogue ----
  const int lrow = (lane >> 4) * 4;
  const int lcol = lane & 15;
#pragma unroll
  for (int m = 0; m < 8; m++) {
#pragma unroll
    for (int n = 0; n < 4; n++) {
      const int r0 = row0 + wm * 128 + m * 16 + lrow;
      const int c  = col0 + wn * 64 + n * 16 + lcol;
      if constexpr (!TRANS_OUT) {
#pragma unroll
        for (int j = 0; j < 4; j++)
          Cb[(long)(r0 + j) * ldc + c] = (OutT)(acc[m][n][j] * alpha);
      } else {
        half4 h;
#pragma unroll
        for (int j = 0; j < 4; j++) h[j] = (f16)(acc[m][n][j] * alpha);
        *(half4*)(&Cb[(long)c * ldc + r0]) = h;
      }
    }
  }
}

__global__ __launch_bounds__(256) void f32_to_f16_k(const float* __restrict__ in,
                                                    f16* __restrict__ out, int n4) {
  const int i = blockIdx.x * 256 + threadIdx.x;
  if (i < n4) {
    const float4 x = ((const float4*)in)[i];
    half4 h;
    h[0] = (f16)x.x; h[1] = (f16)x.y; h[2] = (f16)x.z; h[3] = (f16)x.w;
    ((half4*)out)[i] = h;
  }
}

// out[j][i] = (f16)in[i][j], n x n (n multiple of 64)
__global__ __launch_bounds__(256) void transpose_f32_f16_k(const float* __restrict__ in,
                                                           f16* __restrict__ out, int n) {
  __shared__ float tile[64][65];
  const int bx = blockIdx.x, by = blockIdx.y;
  const int tr = threadIdx.x >> 4;
  const int tc = (threadIdx.x & 15) * 4;
  const int r0 = by * 64, c0 = bx * 64;
#pragma unroll
  for (int i = 0; i < 4; i++) {
    const float4 v = *(const float4*)&in[(long)(r0 + tr + i * 16) * n + c0 + tc];
    tile[tr + i * 16][tc + 0] = v.x;
    tile[tr + i * 16][tc + 1] = v.y;
    tile[tr + i * 16][tc + 2] = v.z;
    tile[tr + i * 16][tc + 3] = v.w;
  }
  __syncthreads();
#pragma unroll
  for (int i = 0; i < 4; i++) {
    const int orow = tr + i * 16;
    half4 h;
#pragma unroll
    for (int j = 0; j < 4; j++) h[j] = (f16)tile[tc + j][orow];
    *(half4*)&out[(long)(c0 + orow) * n + r0 + tc] = h;
  }
}

// one block per row: masked softmax over 2048 f16 scores -> f16 probs
__global__ __launch_bounds__(256) void softmax_mask_k(const f16* __restrict__ S,
                                                      f16* __restrict__ P,
                                                      const int* __restrict__ kmask,
                                                      const int* __restrict__ is_causal_p) {
  const int row = blockIdx.x;
  const int b   = row >> 11;
  const int qi  = row & 2047;
  const int tid = threadIdx.x;
  const int causal = *is_causal_p;

  const f16* srow = S + (long)row * 2048;
  const int* mrow = kmask + (long)b * 2048;

  const half8 x  = ((const half8*)srow)[tid];
  const int4  m0 = ((const int4*)mrow)[tid * 2];
  const int4  m1 = ((const int4*)mrow)[tid * 2 + 1];
  const int   mk[8] = {m0.x, m0.y, m0.z, m0.w, m1.x, m1.y, m1.z, m1.w};
  const int   kb = tid * 8;

  float v[8];
  float vmax = -INFINITY;
#pragma unroll
  for (int e = 0; e < 8; e++) {
    const bool keep = (mk[e] != 0) || (causal && (kb + e > qi));
    v[e] = keep ? (float)x[e] : -INFINITY;
    vmax = fmaxf(vmax, v[e]);
  }
#pragma unroll
  for (int o = 32; o > 0; o >>= 1) vmax = fmaxf(vmax, __shfl_xor(vmax, o, 64));

  __shared__ float red[8];
  if ((tid & 63) == 0) red[tid >> 6] = vmax;
  __syncthreads();
  vmax = fmaxf(fmaxf(red[0], red[1]), fmaxf(red[2], red[3]));

  float p[8];
  float s = 0.f;
#pragma unroll
  for (int e = 0; e < 8; e++) { p[e] = __expf(v[e] - vmax); s += p[e]; }
#pragma unroll
  for (int o = 32; o > 0; o >>= 1) s += __shfl_xor(s, o, 64);
  if ((tid & 63) == 0) red[4 + (tid >> 6)] = s;
  __syncthreads();
  s = red[4] + red[5] + red[6] + red[7];
  const float inv = 1.0f / s;

  half8 h;
#pragma unroll
  for (int e = 0; e < 8; e++) h[e] = (f16)(p[e] * inv);
  ((half8*)(P + (long)row * 2048))[tid] = h;
}

extern "C" void kernel_launch(void* const* d_in, const int* in_sizes, int n_in,
                              void* d_out, int out_size, void* d_ws, size_t ws_size,
                              hipStream_t stream) {
  const float* query = (const float*)d_in[0];
  const float* key   = (const float*)d_in[1];
  const float* value = (const float*)d_in[2];
  const float* Wq    = (const float*)d_in[3];
  const float* Wk    = (const float*)d_in[4];
  const float* Wv    = (const float*)d_in[5];
  const int*   kmask = (const int*)d_in[6];
  const int*   iscau = (const int*)d_in[7];

  char* ws = (char*)d_ws;
  f16* buf1 = (f16*)ws;                          // qf -> vf
  f16* buf2 = (f16*)(ws + ACT_ELEMS * 2);        // WqT|WkT -> q' -> P
  f16* buf3 = (f16*)(ws + 2 * ACT_ELEMS * 2);    // X -> kf -> vT
  f16* w2   = (f16*)(ws + 3 * ACT_ELEMS * 2);    // Wv f16 (persists)
  f16* WqT  = buf2;
  f16* WkT  = buf2 + W_ELEMS;
  f16* Xm   = buf3;                              // X = scale * Wk^T * Wq

  const dim3 blk(256);
  const dim3 blk512(512);
  const int LDSB = 131072;
  const int cw = (int)(W_ELEMS / 4 + 255) / 256;
  const int ca = (int)(ACT_ELEMS / 4 + 255) / 256;
  const float scale = 0.022097086912079608f;     // 1/sqrt(2048)
  const long SB = (long)SEQ * SEQ;

  hipFuncSetAttribute((const void*)&gemm256_bt<f16, false>,
                      hipFuncAttributeMaxDynamicSharedMemorySize, LDSB);
  hipFuncSetAttribute((const void*)&gemm256_bt<f16, true>,
                      hipFuncAttributeMaxDynamicSharedMemorySize, LDSB);
  hipFuncSetAttribute((const void*)&gemm256_bt<float, false>,
                      hipFuncAttributeMaxDynamicSharedMemorySize, LDSB);

  // ---- weight preprocessing ----
  transpose_f32_f16_k<<<dim3(32, 32), blk, 0, stream>>>(Wq, WqT, MODELD);
  transpose_f32_f16_k<<<dim3(32, 32), blk, 0, stream>>>(Wk, WkT, MODELD);
  f32_to_f16_k<<<cw, blk, 0, stream>>>(Wv, w2, (int)(W_ELEMS / 4));

  // X = scale * Wk^T * Wq   (2048^3, writes buf3)
  gemm256_bt<f16, false><<<64, blk512, LDSB, stream>>>(
      WkT, MODELD, 0, WqT, MODELD, 0, Xm, MODELD, 0, MODELD, scale, 8, 8);

  // q' = query * X^T   (16384 x 2048 x 2048)
  f32_to_f16_k<<<ca, blk, 0, stream>>>(query, buf1, (int)(ACT_ELEMS / 4));
  gemm256_bt<f16, false><<<512, blk512, LDSB, stream>>>(
      buf1, MODELD, 0, Xm, MODELD, 0, buf2, MODELD, 0, MODELD, 1.0f, 8, 64);

  // scores(f16, in d_out) = q' * key^T   (batched)
  f32_to_f16_k<<<ca, blk, 0, stream>>>(key, buf3, (int)(ACT_ELEMS / 4));
  gemm256_bt<f16, false><<<512, blk512, LDSB, stream>>>(
      buf2, MODELD, SB, buf3, MODELD, SB, (f16*)d_out, SEQ, SB, MODELD, 1.0f, 8, 8);

  // softmax: d_out(f16) -> P in buf2
  softmax_mask_k<<<NB * SEQ, blk, 0, stream>>>((const f16*)d_out, buf2, kmask, iscau);

  // v^T = (value * Wv^T)^T, transposed epilogue
  f32_to_f16_k<<<ca, blk, 0, stream>>>(value, buf1, (int)(ACT_ELEMS / 4));
  gemm256_bt<f16, true><<<512, blk512, LDSB, stream>>>(
      buf1, MODELD, SB, w2, MODELD, 0, buf3, SEQ, SB, MODELD, 1.0f, 8, 8);

  // out(f32) = P * v = P * (v^T)^T
  gemm256_bt<float, false><<<512, blk512, LDSB, stream>>>(
      buf2, SEQ, SB, buf3, SEQ, SB, (float*)d_out, SEQ, SB, SEQ, 1.0f, 8, 8);

  (void)in_sizes; (void)n_in; (void)out_size; (void)ws_size;
}

// Round 3
// 1127.310 us; speedup vs baseline: 1.3450x; 1.0049x over previous
//
#include <hip/hip_runtime.h>
#include <cstdint>

typedef _Float16 f16;
typedef __attribute__((ext_vector_type(8))) _Float16 half8;
typedef __attribute__((ext_vector_type(4))) _Float16 half4;
typedef __attribute__((ext_vector_type(4))) float f32x4;

#define NB    8
#define SEQ   2048
#define MODELD 2048
#define ACT_ELEMS (16384L * 2048L)
#define W_ELEMS   (2048L * 2048L)

__device__ __forceinline__ void gld_lds16(const void* g, void* l) {
  __builtin_amdgcn_global_load_lds(
      (const __attribute__((address_space(1))) unsigned int*)(uintptr_t)g,
      (__attribute__((address_space(3))) unsigned int*)(uintptr_t)l,
      16, 0, 0);
}

// C = alpha * A * B^T.  A: M x K row-major, B: N x K row-major (K contiguous).
// 256x256 tile, BK=32, 8 waves (2Mx4N), per-wave 128x64 output.
// LDS: 4-slot ring (A 4x16KB | B 4x16KB = 128KB dynamic). While computing
// K-tile t (slot t&3), tile t+3 is staged into slot (t+3)&3 == (t-1)&3 (free
// since all reads of tile t-1 precede iter t-1's barrier).
//
// ONE barrier per K-tile (was 4). Correctness:
//  - WAR (stage overwrites slot sw): every ds_read of tile t-1 is issued
//    before iter t-1's barrier; iter t's STAGE is issued after it.
//  - RAW (reads of tile t+1): this wave's vmcnt(8) retires its 4 loads for
//    tile t+1 (issued iter t-2); the barrier publishes all waves' LDS writes;
//    iter t+1's reads follow the barrier.
//  - Max wave skew = 1 iteration; all accesses in the skew window touch
//    either sealed slots or registers. Waves de-phase => ds_read/MFMA/stage
//    overlap across waves; setprio(1) prioritizes the MFMA-entering waves.
template <typename OutT, bool TRANS_OUT>
__global__ __launch_bounds__(512, 2) void gemm256_bt(
    const f16* __restrict__ A, long lda, long sA,
    const f16* __restrict__ Bm, long ldb, long sB,
    OutT* __restrict__ C, long ldc, long sC,
    int K, float alpha, int tilesX, int tilesY)
{
  extern __shared__ f16 smem[];
  const int tid  = threadIdx.x;
  const int lane = tid & 63;
  const int wave = tid >> 6;

  // ---- XCD-contiguous supertile decode (total % 8 == 0 by construction) ----
  const unsigned total = gridDim.x;
  const unsigned per   = total >> 3;
  const unsigned wid   = (blockIdx.x & 7) * per + (blockIdx.x >> 3);
  const unsigned perB  = (unsigned)(tilesX * tilesY);
  const unsigned bz    = wid / perB;
  unsigned t0          = wid - bz * perB;
  const unsigned sx    = (unsigned)tilesX >> 2;      // supertile columns
  const unsigned st    = t0 >> 4;                    // 16 blocks / supertile
  const unsigned w     = t0 & 15;
  const unsigned sr    = st / sx;
  const unsigned sc    = st - sr * sx;
  const int by = (int)(sr * 4 + (w >> 2));
  const int bx = (int)(sc * 4 + (w & 3));

  const f16* Ab = A + (long)bz * sA;
  const f16* Bb = Bm + (long)bz * sB;
  OutT*      Cb = C + (long)bz * sC;

  const int row0 = by * 256;
  const int col0 = bx * 256;

  const int r16 = lane & 15;     // staged row within 16-row group
  const int kc  = lane >> 4;     // staged k-chunk (8 f16)
  const int wm  = wave >> 2;     // 0..1  (row half)
  const int wn  = wave & 3;      // 0..3  (col quarter)

  f16* ldsA = smem;              // 4 slots x 8192 f16
  f16* ldsB = smem + 32768;      // 4 slots x 8192 f16

  const int T = K >> 5;          // K-tiles of 32

  f32x4 acc[8][4];
#pragma unroll
  for (int m = 0; m < 8; m++)
#pragma unroll
    for (int n = 0; n < 4; n++) {
      f32x4 z = {0.f, 0.f, 0.f, 0.f};
      acc[m][n] = z;
    }

  // stage: piece p stages group g = p*8+wave (16 rows x 32 k = 1KB per wave)
#define STAGE_A(u_, sw_)                                                   \
  do {                                                                     \
    const long ku_ = (long)(u_) * 32;                                      \
    _Pragma("unroll")                                                      \
    for (int p_ = 0; p_ < 2; ++p_) {                                       \
      const int g_ = p_ * 8 + wave;                                        \
      gld_lds16(Ab + (long)(row0 + g_ * 16 + r16) * lda + ku_ + kc * 8,    \
                ldsA + (sw_) * 8192 + g_ * 512);                           \
    }                                                                      \
  } while (0)
#define STAGE_B(u_, sw_)                                                   \
  do {                                                                     \
    const long ku_ = (long)(u_) * 32;                                      \
    _Pragma("unroll")                                                      \
    for (int p_ = 0; p_ < 2; ++p_) {                                       \
      const int g_ = p_ * 8 + wave;                                        \
      gld_lds16(Bb + (long)(col0 + g_ * 16 + r16) * ldb + ku_ + kc * 8,    \
                ldsB + (sw_) * 8192 + g_ * 512);                           \
    }                                                                      \
  } while (0)

  // ---- prologue: stage tiles 0,1,2 (12 loads/thread) ----
  const int u1 = (T > 1) ? 1 : 0;
  const int u2 = (T > 2) ? 2 : T - 1;
  STAGE_A(0, 0);  STAGE_B(0, 0);
  STAGE_A(u1, 1); STAGE_B(u1, 1);
  STAGE_A(u2, 2); STAGE_B(u2, 2);
  asm volatile("s_waitcnt vmcnt(8)" ::: "memory");   // tile 0 landed
  __builtin_amdgcn_s_barrier();

  for (int t = 0; t < T; ++t) {
    const int s  = t & 3;
    const int sw = (t + 3) & 3;                       // == (t-1)&3: free slot
    const int u  = (t + 3 < T) ? t + 3 : T - 1;       // clamp: uniform counts
    const f16* As = ldsA + s * 8192;
    const f16* Bs = ldsB + s * 8192;

    half8 af[4], bf[4];

    // ---------- half 0: m-frags 0..3 ----------
#pragma unroll
    for (int m = 0; m < 4; m++)
      af[m] = *(const half8*)(As + (wm * 8 + m) * 512 + lane * 8);
#pragma unroll
    for (int n = 0; n < 4; n++)
      bf[n] = *(const half8*)(Bs + (wn * 4 + n) * 512 + lane * 8);
    STAGE_A(u, sw);
    __builtin_amdgcn_s_setprio(1);
#pragma unroll
    for (int m = 0; m < 4; m++)
#pragma unroll
      for (int n = 0; n < 4; n++)
        acc[m][n] = __builtin_amdgcn_mfma_f32_16x16x32_f16(af[m], bf[n], acc[m][n], 0, 0, 0);
    __builtin_amdgcn_s_setprio(0);

    // ---------- half 1: m-frags 4..7 (reuse bf) ----------
#pragma unroll
    for (int m = 0; m < 4; m++)
      af[m] = *(const half8*)(As + (wm * 8 + 4 + m) * 512 + lane * 8);
    STAGE_B(u, sw);
    // counted wait: outstanding <= 8 = {tile t+2: 4, tile t+3: 4};
    // guarantees tile t+1 (issued iter t-2) fully landed in LDS.
    asm volatile("s_waitcnt vmcnt(8)" ::: "memory");
    __builtin_amdgcn_s_barrier();   // the ONLY barrier this iteration
    __builtin_amdgcn_s_setprio(1);
#pragma unroll
    for (int m = 0; m < 4; m++)
#pragma unroll
      for (int n = 0; n < 4; n++)
        acc[4 + m][n] = __builtin_amdgcn_mfma_f32_16x16x32_f16(af[m], bf[n], acc[4 + m][n], 0, 0, 0);
    __builtin_amdgcn_s_setprio(0);
  }
#undef STAGE_A
#undef STAGE_B

  // drain staging before the block can retire (LDS may be reallocated)
  asm volatile("s_waitcnt vmcnt(0)" ::: "memory");

  // ---- epilogue ----
  const int lrow = (lane >> 4) * 4;
  const int lcol = lane & 15;
#pragma unroll
  for (int m = 0; m < 8; m++) {
#pragma unroll
    for (int n = 0; n < 4; n++) {
      const int r0 = row0 + wm * 128 + m * 16 + lrow;
      const int c  = col0 + wn * 64 + n * 16 + lcol;
      if constexpr (!TRANS_OUT) {
#pragma unroll
        for (int j = 0; j < 4; j++)
          Cb[(long)(r0 + j) * ldc + c] = (OutT)(acc[m][n][j] * alpha);
      } else {
        half4 h;
#pragma unroll
        for (int j = 0; j < 4; j++) h[j] = (f16)(acc[m][n][j] * alpha);
        *(half4*)(&Cb[(long)c * ldc + r0]) = h;
      }
    }
  }
}

__global__ __launch_bounds__(256) void f32_to_f16_k(const float* __restrict__ in,
                                                    f16* __restrict__ out, int n4) {
  const int i = blockIdx.x * 256 + threadIdx.x;
  if (i < n4) {
    const float4 x = ((const float4*)in)[i];
    half4 h;
    h[0] = (f16)x.x; h[1] = (f16)x.y; h[2] = (f16)x.z; h[3] = (f16)x.w;
    ((half4*)out)[i] = h;
  }
}

// out[j][i] = (f16)in[i][j], n x n (n multiple of 64)
__global__ __launch_bounds__(256) void transpose_f32_f16_k(const float* __restrict__ in,
                                                           f16* __restrict__ out, int n) {
  __shared__ float tile[64][65];
  const int bx = blockIdx.x, by = blockIdx.y;
  const int tr = threadIdx.x >> 4;
  const int tc = (threadIdx.x & 15) * 4;
  const int r0 = by * 64, c0 = bx * 64;
#pragma unroll
  for (int i = 0; i < 4; i++) {
    const float4 v = *(const float4*)&in[(long)(r0 + tr + i * 16) * n + c0 + tc];
    tile[tr + i * 16][tc + 0] = v.x;
    tile[tr + i * 16][tc + 1] = v.y;
    tile[tr + i * 16][tc + 2] = v.z;
    tile[tr + i * 16][tc + 3] = v.w;
  }
  __syncthreads();
#pragma unroll
  for (int i = 0; i < 4; i++) {
    const int orow = tr + i * 16;
    half4 h;
#pragma unroll
    for (int j = 0; j < 4; j++) h[j] = (f16)tile[tc + j][orow];
    *(half4*)&out[(long)(c0 + orow) * n + r0 + tc] = h;
  }
}

// one block per row: masked softmax over 2048 f16 scores -> f16 probs
__global__ __launch_bounds__(256) void softmax_mask_k(const f16* __restrict__ S,
                                                      f16* __restrict__ P,
                                                      const int* __restrict__ kmask,
                                                      const int* __restrict__ is_causal_p) {
  const int row = blockIdx.x;
  const int b   = row >> 11;
  const int qi  = row & 2047;
  const int tid = threadIdx.x;
  const int causal = *is_causal_p;

  const f16* srow = S + (long)row * 2048;
  const int* mrow = kmask + (long)b * 2048;

  const half8 x  = ((const half8*)srow)[tid];
  const int4  m0 = ((const int4*)mrow)[tid * 2];
  const int4  m1 = ((const int4*)mrow)[tid * 2 + 1];
  const int   mk[8] = {m0.x, m0.y, m0.z, m0.w, m1.x, m1.y, m1.z, m1.w};
  const int   kb = tid * 8;

  float v[8];
  float vmax = -INFINITY;
#pragma unroll
  for (int e = 0; e < 8; e++) {
    const bool keep = (mk[e] != 0) || (causal && (kb + e > qi));
    v[e] = keep ? (float)x[e] : -INFINITY;
    vmax = fmaxf(vmax, v[e]);
  }
#pragma unroll
  for (int o = 32; o > 0; o >>= 1) vmax = fmaxf(vmax, __shfl_xor(vmax, o, 64));

  __shared__ float red[8];
  if ((tid & 63) == 0) red[tid >> 6] = vmax;
  __syncthreads();
  vmax = fmaxf(fmaxf(red[0], red[1]), fmaxf(red[2], red[3]));

  float p[8];
  float s = 0.f;
#pragma unroll
  for (int e = 0; e < 8; e++) { p[e] = __expf(v[e] - vmax); s += p[e]; }
#pragma unroll
  for (int o = 32; o > 0; o >>= 1) s += __shfl_xor(s, o, 64);
  if ((tid & 63) == 0) red[4 + (tid >> 6)] = s;
  __syncthreads();
  s = red[4] + red[5] + red[6] + red[7];
  const float inv = 1.0f / s;

  half8 h;
#pragma unroll
  for (int e = 0; e < 8; e++) h[e] = (f16)(p[e] * inv);
  ((half8*)(P + (long)row * 2048))[tid] = h;
}

extern "C" void kernel_launch(void* const* d_in, const int* in_sizes, int n_in,
                              void* d_out, int out_size, void* d_ws, size_t ws_size,
                              hipStream_t stream) {
  const float* query = (const float*)d_in[0];
  const float* key   = (const float*)d_in[1];
  const float* value = (const float*)d_in[2];
  const float* Wq    = (const float*)d_in[3];
  const float* Wk    = (const float*)d_in[4];
  const float* Wv    = (const float*)d_in[5];
  const int*   kmask = (const int*)d_in[6];
  const int*   iscau = (const int*)d_in[7];

  char* ws = (char*)d_ws;
  f16* buf1 = (f16*)ws;                          // qf -> vf
  f16* buf2 = (f16*)(ws + ACT_ELEMS * 2);        // WqT|WkT -> q' -> P
  f16* buf3 = (f16*)(ws + 2 * ACT_ELEMS * 2);    // X -> kf -> vT
  f16* w2   = (f16*)(ws + 3 * ACT_ELEMS * 2);    // Wv f16 (persists)
  f16* WqT  = buf2;
  f16* WkT  = buf2 + W_ELEMS;
  f16* Xm   = buf3;                              // X = scale * Wk^T * Wq

  const dim3 blk(256);
  const dim3 blk512(512);
  const int LDSB = 131072;
  const int cw = (int)(W_ELEMS / 4 + 255) / 256;
  const int ca = (int)(ACT_ELEMS / 4 + 255) / 256;
  const float scale = 0.022097086912079608f;     // 1/sqrt(2048)
  const long SB = (long)SEQ * SEQ;

  hipFuncSetAttribute((const void*)&gemm256_bt<f16, false>,
                      hipFuncAttributeMaxDynamicSharedMemorySize, LDSB);
  hipFuncSetAttribute((const void*)&gemm256_bt<f16, true>,
                      hipFuncAttributeMaxDynamicSharedMemorySize, LDSB);
  hipFuncSetAttribute((const void*)&gemm256_bt<float, false>,
                      hipFuncAttributeMaxDynamicSharedMemorySize, LDSB);

  // ---- weight preprocessing ----
  transpose_f32_f16_k<<<dim3(32, 32), blk, 0, stream>>>(Wq, WqT, MODELD);
  transpose_f32_f16_k<<<dim3(32, 32), blk, 0, stream>>>(Wk, WkT, MODELD);
  f32_to_f16_k<<<cw, blk, 0, stream>>>(Wv, w2, (int)(W_ELEMS / 4));

  // X = scale * Wk^T * Wq   (2048^3, writes buf3)
  gemm256_bt<f16, false><<<64, blk512, LDSB, stream>>>(
      WkT, MODELD, 0, WqT, MODELD, 0, Xm, MODELD, 0, MODELD, scale, 8, 8);

  // q' = query * X^T   (16384 x 2048 x 2048)
  f32_to_f16_k<<<ca, blk, 0, stream>>>(query, buf1, (int)(ACT_ELEMS / 4));
  gemm256_bt<f16, false><<<512, blk512, LDSB, stream>>>(
      buf1, MODELD, 0, Xm, MODELD, 0, buf2, MODELD, 0, MODELD, 1.0f, 8, 64);

  // scores(f16, in d_out) = q' * key^T   (batched)
  f32_to_f16_k<<<ca, blk, 0, stream>>>(key, buf3, (int)(ACT_ELEMS / 4));
  gemm256_bt<f16, false><<<512, blk512, LDSB, stream>>>(
      buf2, MODELD, SB, buf3, MODELD, SB, (f16*)d_out, SEQ, SB, MODELD, 1.0f, 8, 8);

  // softmax: d_out(f16) -> P in buf2
  softmax_mask_k<<<NB * SEQ, blk, 0, stream>>>((const f16*)d_out, buf2, kmask, iscau);

  // v^T = (value * Wv^T)^T, transposed epilogue
  f32_to_f16_k<<<ca, blk, 0, stream>>>(value, buf1, (int)(ACT_ELEMS / 4));
  gemm256_bt<f16, true><<<512, blk512, LDSB, stream>>>(
      buf1, MODELD, SB, w2, MODELD, 0, buf3, SEQ, SB, MODELD, 1.0f, 8, 8);

  // out(f32) = P * v = P * (v^T)^T
  gemm256_bt<float, false><<<512, blk512, LDSB, stream>>>(
      buf2, SEQ, SB, buf3, SEQ, SB, (float*)d_out, SEQ, SB, SEQ, 1.0f, 8, 8);

  (void)in_sizes; (void)n_in; (void)out_size; (void)ws_size;
}